// Round 3
// baseline (171.744 us; speedup 1.0000x reference)
//
#include <hip/hip_runtime.h>

// AntModel: counts flow through 3 routing layers.
//   dest_k[s] = argmax_j W_k[s, j]   (first max index)
//   layer: out[b, dest[s]] += counts[b, s]; relu == identity (counts >= 0)
// Composition: out[b, dest3[dest2[dest1[s]]]] += x[b, s].
//
// R2 -> R3: argmax was latency-bound (VGPR=12, serialized loads, 1.37 TB/s).
// Batch 8 float4 loads into registers before the compare chain to get 8
// outstanding 1KB loads/wave; per-lane tie-break dropped (indices monotone
// per lane, strict > keeps first max); scatter fdest reads vectorized.

#define N_IN   4096
#define N_MID  4096
#define N_OUT  1024
#define BATCH  256

template <int NCOLS>
__device__ __forceinline__ void row_argmax(const float* __restrict__ W, int row,
                                           int* __restrict__ dest) {
    const int lane = threadIdx.x & 63;
    const float4* __restrict__ p =
        reinterpret_cast<const float4*>(W + (size_t)row * NCOLS);
    float bv = -__builtin_huge_valf();
    int bi = 0;
    constexpr int TOT = NCOLS / 256;            // float4s per lane (16 or 4)
    constexpr int BS  = TOT >= 8 ? 8 : TOT;     // 8 loads in flight, 32 VGPRs
    #pragma unroll
    for (int o = 0; o < TOT; o += BS) {
        float4 v[BS];
        #pragma unroll
        for (int t = 0; t < BS; ++t) v[t] = p[(size_t)(o + t) * 64 + lane];
        #pragma unroll
        for (int t = 0; t < BS; ++t) {
            const int c = (o + t) * 256 + lane * 4;
            // per-lane indices strictly increase -> '>' keeps first max
            if (v[t].x > bv) { bv = v[t].x; bi = c + 0; }
            if (v[t].y > bv) { bv = v[t].y; bi = c + 1; }
            if (v[t].z > bv) { bv = v[t].z; bi = c + 2; }
            if (v[t].w > bv) { bv = v[t].w; bi = c + 3; }
        }
    }
    // wave-64 butterfly; (value desc, index asc) total order -> xor-safe
    #pragma unroll
    for (int off = 1; off < 64; off <<= 1) {
        float ov = __shfl_xor(bv, off, 64);
        int   oi = __shfl_xor(bi, off, 64);
        if (ov > bv || (ov == bv && oi < bi)) { bv = ov; bi = oi; }
    }
    if (lane == 0) dest[row] = bi;
}

__global__ __launch_bounds__(256) void argmax_all_kernel(
    const float* __restrict__ W1, const float* __restrict__ W2,
    const float* __restrict__ W3, int* __restrict__ dest1,
    int* __restrict__ dest2, int* __restrict__ dest3) {
    const int wave = (blockIdx.x * blockDim.x + threadIdx.x) >> 6;
    if (wave < N_IN) {
        row_argmax<N_MID>(W1, wave, dest1);
    } else if (wave < N_IN + N_MID) {
        row_argmax<N_MID>(W2, wave - N_IN, dest2);
    } else {
        row_argmax<N_OUT>(W3, wave - (N_IN + N_MID), dest3);
    }
}

__global__ __launch_bounds__(256) void compose_kernel(
    const int* __restrict__ dest1, const int* __restrict__ dest2,
    const int* __restrict__ dest3, int* __restrict__ fdest) {
    const int s = blockIdx.x * blockDim.x + threadIdx.x;
    if (s < N_IN) fdest[s] = dest3[dest2[dest1[s]]];
}

__global__ __launch_bounds__(256) void scatter_kernel(
    const int* __restrict__ x, const int* __restrict__ fdest,
    float* __restrict__ out) {
    __shared__ int cnt[N_OUT];
    const int b = blockIdx.x;
    for (int i = threadIdx.x; i < N_OUT; i += 256) cnt[i] = 0;
    __syncthreads();
    const int4* __restrict__ x4 =
        reinterpret_cast<const int4*>(x + (size_t)b * N_IN);
    const int4* __restrict__ f4 = reinterpret_cast<const int4*>(fdest);
    for (int q = threadIdx.x; q < N_IN / 4; q += 256) {
        int4 v = x4[q];
        int4 d = f4[q];
        atomicAdd(&cnt[d.x], v.x);
        atomicAdd(&cnt[d.y], v.y);
        atomicAdd(&cnt[d.z], v.z);
        atomicAdd(&cnt[d.w], v.w);
    }
    __syncthreads();
    float* __restrict__ ob = out + (size_t)b * N_OUT;
    for (int i = threadIdx.x; i < N_OUT; i += 256) ob[i] = (float)cnt[i];
}

extern "C" void kernel_launch(void* const* d_in, const int* in_sizes, int n_in,
                              void* d_out, int out_size, void* d_ws, size_t ws_size,
                              hipStream_t stream) {
    const int*   x  = (const int*)d_in[0];
    const float* W1 = (const float*)d_in[1];
    const float* W2 = (const float*)d_in[2];
    const float* W3 = (const float*)d_in[3];
    float* out = (float*)d_out;

    int* ws    = (int*)d_ws;
    int* dest1 = ws;               // [4096]
    int* dest2 = ws + N_IN;        // [4096]
    int* dest3 = ws + 2 * N_IN;    // [4096]
    int* fdest = ws + 3 * N_IN;    // [4096]

    const int total_waves = N_IN + N_MID + N_MID;  // 12288 rows, 1 wave each
    argmax_all_kernel<<<total_waves / 4, 256, 0, stream>>>(W1, W2, W3,
                                                           dest1, dest2, dest3);
    compose_kernel<<<N_IN / 256, 256, 0, stream>>>(dest1, dest2, dest3, fdest);
    scatter_kernel<<<BATCH, 256, 0, stream>>>(x, fdest, out);
}